// Round 1
// baseline (9.953 us; speedup 1.0000x reference)
//
#include <hip/hip_runtime.h>

#define NN 8192
#define EE 256
#define LL 4

__global__ __launch_bounds__(256) void GraphFilter_kernel(
    const float* __restrict__ emb,   // N*E
    const float* __restrict__ A,     // L*N*N
    const int*   __restrict__ idp,   // 1
    const float* __restrict__ w,     // 2E
    float* __restrict__ out)         // N
{
    const int id   = idp[0];
    const int lane = threadIdx.x & 63;
    const int wave = threadIdx.x >> 6;
    const int j    = blockIdx.x * 4 + wave;       // output row, one wave per row

    // lane l covers elements [4l, 4l+4) of the E=256 dot products
    const int e4 = lane * 4;
    const float4 w1 = *reinterpret_cast<const float4*>(w + e4);
    const float4 w2 = *reinterpret_cast<const float4*>(w + EE + e4);
    const float4 ei = *reinterpret_cast<const float4*>(emb + (size_t)id * EE + e4);
    const float4 er = *reinterpret_cast<const float4*>(emb + (size_t)j  * EE + e4);

    float s = ei.x * w2.x + ei.y * w2.y + ei.z * w2.z + ei.w * w2.w;
    float d = er.x * w1.x + er.y * w1.y + er.z * w1.z + er.w * w1.w;

    // 64-lane butterfly reduction for both partial dots
    #pragma unroll
    for (int off = 32; off >= 1; off >>= 1) {
        s += __shfl_xor(s, off, 64);
        d += __shfl_xor(d, off, 64);
    }

    if (lane == 0) {
        float r = d + s;
        r = r > 0.0f ? r : 0.0f;
        const size_t base = (size_t)id * NN + j;
        const float a0 = A[base];
        const float a1 = A[base + (size_t)1 * NN * NN];
        const float a2 = A[base + (size_t)2 * NN * NN];
        const float a3 = A[base + (size_t)3 * NN * NN];
        const float asum = ((a0 + a1) + a2) + a3;
        out[j] = (asum != 0.0f) ? asum * r : 0.0f;
    }
}

extern "C" void kernel_launch(void* const* d_in, const int* in_sizes, int n_in,
                              void* d_out, int out_size, void* d_ws, size_t ws_size,
                              hipStream_t stream) {
    const float* emb = (const float*)d_in[0];
    const float* A   = (const float*)d_in[1];
    const int*   idp = (const int*)d_in[2];
    const float* w   = (const float*)d_in[3];
    float* out = (float*)d_out;

    dim3 grid(NN / 4);   // 2048 blocks x 4 waves = 8192 waves, one per row
    dim3 block(256);
    GraphFilter_kernel<<<grid, block, 0, stream>>>(emb, A, idp, w, out);
}

// Round 2
// 9.368 us; speedup vs baseline: 1.0625x; 1.0625x over previous
//
#include <hip/hip_runtime.h>

#define NN 8192
#define EE 256
#define LL 4
#define ROWS 4   // rows per wave

__global__ __launch_bounds__(256) void GraphFilter_kernel(
    const float* __restrict__ emb,   // N*E
    const float* __restrict__ A,     // L*N*N
    const int*   __restrict__ idp,   // 1
    const float* __restrict__ w,     // 2E
    float* __restrict__ out)         // N
{
    const int id   = idp[0];
    const int lane = threadIdx.x & 63;
    const int wv   = __builtin_amdgcn_readfirstlane((int)(threadIdx.x >> 6));
    const int j0   = (blockIdx.x * 4 + wv) * ROWS;   // first of 4 rows for this wave

    // ---- wave-uniform A loads (issue first; scalar loads, latency hidden) ----
    float asum0 = 0.f, asum1 = 0.f, asum2 = 0.f, asum3 = 0.f;
    #pragma unroll
    for (int l = 0; l < LL; ++l) {
        const float* Ap = A + (size_t)l * NN * NN + (size_t)id * NN + j0;
        asum0 += Ap[0];
        asum1 += Ap[1];
        asum2 += Ap[2];
        asum3 += Ap[3];
    }

    // ---- per-lane slice of the E=256 dot products ----
    const int e4 = lane * 4;
    const float4 w1 = *reinterpret_cast<const float4*>(w + e4);
    const float4 w2 = *reinterpret_cast<const float4*>(w + EE + e4);
    const float4 ei = *reinterpret_cast<const float4*>(emb + (size_t)id * EE + e4);

    const float4 er0 = *reinterpret_cast<const float4*>(emb + (size_t)(j0 + 0) * EE + e4);
    const float4 er1 = *reinterpret_cast<const float4*>(emb + (size_t)(j0 + 1) * EE + e4);
    const float4 er2 = *reinterpret_cast<const float4*>(emb + (size_t)(j0 + 2) * EE + e4);
    const float4 er3 = *reinterpret_cast<const float4*>(emb + (size_t)(j0 + 3) * EE + e4);

    float s  = ei.x * w2.x + ei.y * w2.y + ei.z * w2.z + ei.w * w2.w;
    float d0 = er0.x * w1.x + er0.y * w1.y + er0.z * w1.z + er0.w * w1.w;
    float d1 = er1.x * w1.x + er1.y * w1.y + er1.z * w1.z + er1.w * w1.w;
    float d2 = er2.x * w1.x + er2.y * w1.y + er2.z * w1.z + er2.w * w1.w;
    float d3 = er3.x * w1.x + er3.y * w1.y + er3.z * w1.z + er3.w * w1.w;

    // ---- 5 independent butterfly chains, interleaved ----
    #pragma unroll
    for (int off = 32; off >= 1; off >>= 1) {
        s  += __shfl_xor(s,  off, 64);
        d0 += __shfl_xor(d0, off, 64);
        d1 += __shfl_xor(d1, off, 64);
        d2 += __shfl_xor(d2, off, 64);
        d3 += __shfl_xor(d3, off, 64);
    }

    if (lane == 0) {
        const float r0 = fmaxf(d0 + s, 0.f);
        const float r1 = fmaxf(d1 + s, 0.f);
        const float r2 = fmaxf(d2 + s, 0.f);
        const float r3 = fmaxf(d3 + s, 0.f);
        float4 o;
        o.x = (asum0 != 0.0f) ? asum0 * r0 : 0.0f;
        o.y = (asum1 != 0.0f) ? asum1 * r1 : 0.0f;
        o.z = (asum2 != 0.0f) ? asum2 * r2 : 0.0f;
        o.w = (asum3 != 0.0f) ? asum3 * r3 : 0.0f;
        *reinterpret_cast<float4*>(out + j0) = o;
    }
}

extern "C" void kernel_launch(void* const* d_in, const int* in_sizes, int n_in,
                              void* d_out, int out_size, void* d_ws, size_t ws_size,
                              hipStream_t stream) {
    const float* emb = (const float*)d_in[0];
    const float* A   = (const float*)d_in[1];
    const int*   idp = (const int*)d_in[2];
    const float* w   = (const float*)d_in[3];
    float* out = (float*)d_out;

    dim3 grid(NN / (4 * ROWS));   // 512 blocks x 4 waves x 4 rows = 8192 rows
    dim3 block(256);
    GraphFilter_kernel<<<grid, block, 0, stream>>>(emb, A, idp, w, out);
}